// Round 4
// baseline (294.478 us; speedup 1.0000x reference)
//
#include <hip/hip_runtime.h>
#include <math.h>

#define PI_F 3.14159265358979323846f

constexpr int Bq = 8, Lq = 1024, Sq = 1024, Hq = 8, Dq = 64;

typedef short short8 __attribute__((ext_vector_type(8)));
typedef float f4v __attribute__((ext_vector_type(4)));
typedef unsigned short ushort_t;

static __device__ __forceinline__ ushort_t f2bf(float x) {
  union { float f; unsigned u; } v; v.f = x;
  unsigned r = v.u + 0x7fffu + ((v.u >> 16) & 1u);   // RNE
  return (ushort_t)(r >> 16);
}
static __device__ __forceinline__ float bf2f(ushort_t b) {
  union { unsigned u; float f; } v; v.u = ((unsigned)b) << 16;
  return v.f;
}
static __device__ __forceinline__ f4v mfma16(short8 a, short8 b, f4v c) {
  return __builtin_amdgcn_mfma_f32_16x16x32_bf16(a, b, c, 0, 0, 0);
}
// q~' from q~: pairs (re,im) -> (im,-re); bf16 negate = sign-bit flip
static __device__ __forceinline__ short8 primef(short8 q) {
  short8 r;
#pragma unroll
  for (int i = 0; i < 4; ++i) {
    r[2 * i]     = q[2 * i + 1];
    r[2 * i + 1] = (short)(((ushort_t)q[2 * i]) ^ 0x8000u);
  }
  return r;
}

// ---------------------------------------------------------------------------
// Shared state-math: angles -> diag -> WHT -> st[32] interleaved (re,im) f32
// ---------------------------------------------------------------------------
static __device__ __forceinline__ void state_vec(
    const float* __restrict__ x, const float lw[4][64], const float lb[4],
    int n, float st[32])
{
  const float4* xp = (const float4*)(x + (size_t)n * 64);
  float a0 = lb[0], a1 = lb[1], a2 = lb[2], a3 = lb[3];
#pragma unroll
  for (int i = 0; i < 16; ++i) {
    float4 v = xp[i];
    a0 += v.x * lw[0][4*i] + v.y * lw[0][4*i+1] + v.z * lw[0][4*i+2] + v.w * lw[0][4*i+3];
    a1 += v.x * lw[1][4*i] + v.y * lw[1][4*i+1] + v.z * lw[1][4*i+2] + v.w * lw[1][4*i+3];
    a2 += v.x * lw[2][4*i] + v.y * lw[2][4*i+1] + v.z * lw[2][4*i+2] + v.w * lw[2][4*i+3];
    a3 += v.x * lw[3][4*i] + v.y * lw[3][4*i+1] + v.z * lw[3][4*i+2] + v.w * lw[3][4*i+3];
  }
  a0 = tanhf(a0) * PI_F; a1 = tanhf(a1) * PI_F;
  a2 = tanhf(a2) * PI_F; a3 = tanhf(a3) * PI_F;
  float p01 = a0 * a1, p12 = a1 * a2, p23 = a2 * a3;

  float dr[16], di[16];
#pragma unroll
  for (int d = 0; d < 16; ++d) {
    float s0 = (d & 8) ? -1.f : 1.f;
    float s1 = (d & 4) ? -1.f : 1.f;
    float s2 = (d & 2) ? -1.f : 1.f;
    float s3 = (d & 1) ? -1.f : 1.f;
    float arg = a0*s0 + a1*s1 + a2*s2 + a3*s3
              + p01*s0*s1 + p12*s1*s2 + p23*s2*s3;
    float sn, cs;
    sincosf(0.5f * arg, &sn, &cs);
    dr[d] = cs; di[d] = -sn;
  }
  float hr[16], hi[16];
#pragma unroll
  for (int i = 0; i < 16; ++i) { hr[i] = dr[i]; hi[i] = di[i]; }
#pragma unroll
  for (int stp = 1; stp < 16; stp <<= 1) {
#pragma unroll
    for (int i = 0; i < 16; ++i) {
      if (!(i & stp)) {
        float xr = hr[i], yr = hr[i + stp];
        hr[i] = xr + yr; hr[i + stp] = xr - yr;
        float xi = hi[i], yi = hi[i + stp];
        hi[i] = xi + yi; hi[i + stp] = xi - yi;
      }
    }
  }
#pragma unroll
  for (int d = 0; d < 16; ++d) {
    st[2*d]   = (dr[d] * hr[d] - di[d] * hi[d]) * 0.0625f;
    st[2*d+1] = (dr[d] * hi[d] + di[d] * hr[d]) * 0.0625f;
  }
}

static __device__ __forceinline__ void pack_store(
    const float st[32], ushort_t* __restrict__ outH,
    ushort_t* __restrict__ outL, size_t rb)
{
  unsigned uh[16], ul[16];
#pragma unroll
  for (int d = 0; d < 16; ++d) {
    ushort_t rh = f2bf(st[2*d]), ih = f2bf(st[2*d+1]);
    ushort_t rl = f2bf(st[2*d]   - bf2f(rh));
    ushort_t il = f2bf(st[2*d+1] - bf2f(ih));
    uh[d] = (unsigned)rh | ((unsigned)ih << 16);
    ul[d] = (unsigned)rl | ((unsigned)il << 16);
  }
  uint4* ph = (uint4*)(outH + rb);
  uint4* pl = (uint4*)(outL + rb);
#pragma unroll
  for (int i = 0; i < 4; ++i) {
    ph[i] = make_uint4(uh[4*i], uh[4*i+1], uh[4*i+2], uh[4*i+3]);
    pl[i] = make_uint4(ul[4*i], ul[4*i+1], ul[4*i+2], ul[4*i+3]);
  }
}

// ---------------------------------------------------------------------------
// k_states2: K-side states (unscaled).  [(b*8+h)*1024 + l][32] bf16 hi/lo.
// ---------------------------------------------------------------------------
__global__ __launch_bounds__(256) void k_states2(
    const float* __restrict__ x, const float* __restrict__ w,
    const float* __restrict__ bias, ushort_t* __restrict__ outH,
    ushort_t* __restrict__ outL)
{
  __shared__ float lw[4][64];
  __shared__ float lb[4];
  int t = threadIdx.x;
  lw[t >> 6][t & 63] = w[t];
  if (t < 4) lb[t] = bias[t];
  __syncthreads();

  int n = blockIdx.x * 256 + t;
  float st[32];
  state_vec(x, lw, lb, n, st);
  int b = n >> 13, l = (n >> 3) & 1023, h = n & 7;
  pack_store(st, outH, outL, ((size_t)(b * Hq + h) * Lq + l) * 32);
}

// ---------------------------------------------------------------------------
// k_csum: C_part[bh][part][32][32] = sum over 512 s of k~ k~^T (f32).
// 128 blocks (bh, part), 256 threads, k~ reconstructed hi+lo.
// ---------------------------------------------------------------------------
__global__ __launch_bounds__(256) void k_csum(
    const ushort_t* __restrict__ KH, const ushort_t* __restrict__ KL,
    float* __restrict__ Cp)
{
  __shared__ float L[128][36];
  int blk = blockIdx.x;
  int bh = blk >> 1, part = blk & 1;
  int t = threadIdx.x;
  int i = t >> 3, j0 = (t & 7) << 2;
  int row = t >> 1, half = (t & 1) << 4;
  const ushort_t* kh0 = KH + ((size_t)bh * 1024 + part * 512) * 32;
  const ushort_t* kl0 = KL + ((size_t)bh * 1024 + part * 512) * 32;
  float a0 = 0.f, a1 = 0.f, a2 = 0.f, a3 = 0.f;
  for (int ch = 0; ch < 4; ++ch) {
    const short8* ph = (const short8*)(kh0 + (size_t)(ch * 128 + row) * 32 + half);
    const short8* pl = (const short8*)(kl0 + (size_t)(ch * 128 + row) * 32 + half);
    short8 h0 = ph[0], h1 = ph[1], l0 = pl[0], l1 = pl[1];
    __syncthreads();
#pragma unroll
    for (int e = 0; e < 8; ++e) {
      L[row][half + e]     = bf2f((ushort_t)h0[e]) + bf2f((ushort_t)l0[e]);
      L[row][half + 8 + e] = bf2f((ushort_t)h1[e]) + bf2f((ushort_t)l1[e]);
    }
    __syncthreads();
#pragma unroll 4
    for (int s = 0; s < 128; ++s) {
      float qi = L[s][i];
      float4 cj = *(const float4*)&L[s][j0];
      a0 += qi * cj.x; a1 += qi * cj.y; a2 += qi * cj.z; a3 += qi * cj.w;
    }
  }
  *(float4*)(Cp + ((size_t)bh * 2 + part) * 1024 + t * 4) =
      make_float4(a0, a1, a2, a3);
}

// ---------------------------------------------------------------------------
// k_vt: V [B][S][H][64] f32  ->  VT [bh][d][s] bf16 hi/lo (transposed per bh)
// ---------------------------------------------------------------------------
__global__ __launch_bounds__(256) void k_vt(
    const float* __restrict__ v, ushort_t* __restrict__ vtH,
    ushort_t* __restrict__ vtL)
{
  __shared__ float tile[64 * 68];
  int bid = blockIdx.x;
  int bh = bid >> 4, s0 = (bid & 15) << 6;
  int b = bh >> 3, h = bh & 7;
  int t = threadIdx.x;
  int sl = t >> 2, dq = (t & 3) << 4;
  const float4* src = (const float4*)(v + (((size_t)b * Sq + s0 + sl) * Hq + h) * 64 + dq);
#pragma unroll
  for (int i = 0; i < 4; ++i)
    *(float4*)&tile[sl * 68 + dq + 4 * i] = src[i];
  __syncthreads();
  int d = t >> 2, sq = (t & 3) << 4;
  unsigned hw[8], lw2[8];
#pragma unroll
  for (int j = 0; j < 8; ++j) {
    float x0 = tile[(sq + 2*j)     * 68 + d];
    float x1 = tile[(sq + 2*j + 1) * 68 + d];
    ushort_t h0 = f2bf(x0), h1 = f2bf(x1);
    ushort_t l0 = f2bf(x0 - bf2f(h0)), l1 = f2bf(x1 - bf2f(h1));
    hw[j]  = (unsigned)h0 | ((unsigned)h1 << 16);
    lw2[j] = (unsigned)l0 | ((unsigned)l1 << 16);
  }
  size_t ob = ((size_t)bh * 64 + d) * 1024 + s0 + sq;
  uint4* oh = (uint4*)(vtH + ob);
  uint4* ol = (uint4*)(vtL + ob);
  oh[0] = make_uint4(hw[0], hw[1], hw[2], hw[3]);
  oh[1] = make_uint4(hw[4], hw[5], hw[6], hw[7]);
  ol[0] = make_uint4(lw2[0], lw2[1], lw2[2], lw2[3]);
  ol[1] = make_uint4(lw2[4], lw2[5], lw2[6], lw2[7]);
}

// ---------------------------------------------------------------------------
// k_states2q: Q-side states, pre-scaled by rsqrt(rowsum + 1e-6) where
// rowsum = q~^T C q~ + q~'^T C q~'  (C summed from the 2 parts in LDS).
// ---------------------------------------------------------------------------
__global__ __launch_bounds__(256) void k_states2q(
    const float* __restrict__ x, const float* __restrict__ w,
    const float* __restrict__ bias, const float* __restrict__ Cp,
    ushort_t* __restrict__ outH, ushort_t* __restrict__ outL)
{
  __shared__ float lw[4][64];
  __shared__ float lb[4];
  __shared__ float Ctab[8 * 1028];     // per-h table, pad 1028 (16B align + banks)
  int t = threadIdx.x;
  lw[t >> 6][t & 63] = w[t];
  if (t < 4) lb[t] = bias[t];
  int b = blockIdx.x >> 5;             // 256 items/block, h fastest -> b fixed
#pragma unroll
  for (int e2 = 0; e2 < 32; ++e2) {
    int idx = e2 * 256 + t;
    int h = idx >> 10, e = idx & 1023;
    size_t cb = ((size_t)(b * 8 + h) * 2) * 1024 + e;
    Ctab[h * 1028 + e] = Cp[cb] + Cp[cb + 1024];
  }
  __syncthreads();

  int n = blockIdx.x * 256 + t;
  float st[32];
  state_vec(x, lw, lb, n, st);

  const float* Ct = &Ctab[(t & 7) * 1028];
  float s1 = 0.f, s2 = 0.f;
#pragma unroll
  for (int i = 0; i < 32; ++i) {
    float yi = 0.f, ypi = 0.f;
#pragma unroll
    for (int j4 = 0; j4 < 8; ++j4) {
      float4 cv = *(const float4*)&Ct[i * 32 + j4 * 4];
      int j = j4 * 4;
      yi  += cv.x * st[j]     + cv.y * st[j+1] + cv.z * st[j+2] + cv.w * st[j+3];
      ypi += cv.x * st[j+1]   - cv.y * st[j]   + cv.z * st[j+3] - cv.w * st[j+2];
    }
    s1 += st[i] * yi;
    float qpi = (i & 1) ? -st[i-1] : st[i+1];
    s2 += qpi * ypi;
  }
  float scl = 1.0f / sqrtf(s1 + s2 + 1e-6f);
#pragma unroll
  for (int i = 0; i < 32; ++i) st[i] *= scl;

  int bb = n >> 13, l = (n >> 3) & 1023, h = n & 7;
  pack_store(st, outH, outL, ((size_t)(bb * Hq + h) * Lq + l) * 32);
}

// ---------------------------------------------------------------------------
// k_fused3: 2048 blocks, 256 threads.  Block = (bh, 32-row l-tile).
// Wave wv: rg = wv&1 (16-row group), sh = wv>>1 (512-s half).
// Per 64-s chunk (fully unrolled, K double-buffered in registers):
//   split-3 fid (pre-normalized q) -> plain attn store
//   -> W hi/lo in swizzled LDS -> split-3 PV MFMA.
// Epilogue: s-half PV reduce via LDS (overlays Wbuf), plain ctx write.
// ---------------------------------------------------------------------------
__global__ __launch_bounds__(256, 4) void k_fused3(
    const ushort_t* __restrict__ QH, const ushort_t* __restrict__ QL,
    const ushort_t* __restrict__ KH, const ushort_t* __restrict__ KL,
    const ushort_t* __restrict__ VTH, const ushort_t* __restrict__ VTL,
    float* __restrict__ attn, float* __restrict__ ctx)
{
  __shared__ char uni[16384];           // Wbuf hi(8K)+lo(8K); redbuf overlays

  int bid = blockIdx.x;                 // 2048 (2048 % 8 == 0 -> bijective)
  int xcd = bid & 7, idx = bid >> 3;
  int bh = (xcd << 3) | (idx >> 5);
  int l0 = (idx & 31) << 5;
  int t = threadIdx.x;
  int wv = t >> 6, lane = t & 63;
  int rg = wv & 1, sh = wv >> 1;
  int lh = lane & 15, g = lane >> 4, ko = g << 3;
  int sb0 = sh << 9;

  int lrow = l0 + (rg << 4) + lh;
  size_t qoff = ((size_t)bh * Lq + lrow) * 32 + ko;
  short8 qh  = *(const short8*)(QH + qoff);
  short8 ql  = *(const short8*)(QL + qoff);
  short8 qph = primef(qh), qpl = primef(ql);

  const ushort_t* kbh = KH + ((size_t)bh * Sq + sb0 + lh) * 32 + ko;
  const ushort_t* kbl = KL + ((size_t)bh * Sq + sb0 + lh) * 32 + ko;
  const ushort_t* VHb = VTH + (size_t)bh * 64 * Sq;
  const ushort_t* VLb = VTL + (size_t)bh * 64 * Sq;

  f4v zero = {0.f, 0.f, 0.f, 0.f};
  float* attnRow = attn + ((size_t)bh * Lq + lrow) * Sq;
  char* wbh = uni + wv * 2048;
  char* wbl = uni + 8192 + wv * 2048;
  f4v pv[4] = {zero, zero, zero, zero};

  short8 KHr[2][4], KLr[2][4];
#pragma unroll
  for (int f = 0; f < 4; ++f) {
    KHr[0][f] = *(const short8*)(kbh + f * 512);
    KLr[0][f] = *(const short8*)(kbl + f * 512);
  }

#pragma unroll
  for (int c = 0; c < 8; ++c) {
    const int cur = c & 1, nxt = cur ^ 1;
    if (c < 7) {
#pragma unroll
      for (int f = 0; f < 4; ++f) {
        KHr[nxt][f] = *(const short8*)(kbh + (c + 1) * 2048 + f * 512);
        KLr[nxt][f] = *(const short8*)(kbl + (c + 1) * 2048 + f * 512);
      }
    }
    int s0 = sb0 + (c << 6);
#pragma unroll
    for (int f = 0; f < 4; ++f) {
      f4v fr = mfma16(KHr[cur][f], qh, zero);
      fr = mfma16(KLr[cur][f], qh, fr);
      fr = mfma16(KHr[cur][f], ql, fr);
      f4v fi = mfma16(KHr[cur][f], qph, zero);
      fi = mfma16(KLr[cur][f], qph, fi);
      fi = mfma16(KHr[cur][f], qpl, fi);
      f4v wv4;
#pragma unroll
      for (int r = 0; r < 4; ++r)
        wv4[r] = fr[r] * fr[r] + fi[r] * fi[r];
      *(f4v*)(attnRow + s0 + (f << 4) + (g << 2)) = wv4;
      // hi = truncation (exact prefix), lo = RNE of residual
      union { float f; unsigned u; } c0, c1, c2, c3;
      c0.f = wv4[0]; c1.f = wv4[1]; c2.f = wv4[2]; c3.f = wv4[3];
      unsigned t0 = c0.u & 0xFFFF0000u, t1 = c1.u & 0xFFFF0000u;
      unsigned t2 = c2.u & 0xFFFF0000u, t3 = c3.u & 0xFFFF0000u;
      union { unsigned u; float f; } b0, b1, b2, b3;
      b0.u = t0; b1.u = t1; b2.u = t2; b3.u = t3;
      ushort_t e0 = f2bf(wv4[0] - b0.f), e1 = f2bf(wv4[1] - b1.f);
      ushort_t e2 = f2bf(wv4[2] - b2.f), e3 = f2bf(wv4[3] - b3.f);
      unsigned off = ((unsigned)lh << 7) + ((unsigned)((f << 4) + (g << 2)) << 1);
      off ^= (unsigned)(lh & 7) << 4;
      *(uint2*)(wbh + off) = make_uint2((t0 >> 16) | t1, (t2 >> 16) | t3);
      *(uint2*)(wbl + off) = make_uint2((unsigned)e0 | ((unsigned)e1 << 16),
                                        (unsigned)e2 | ((unsigned)e3 << 16));
    }
#pragma unroll
    for (int ks = 0; ks < 2; ++ks) {
      unsigned aoff = ((unsigned)lh << 7) + (unsigned)((ks << 6) + (ko << 1));
      aoff ^= (unsigned)(lh & 7) << 4;
      short8 wh = *(const short8*)(wbh + aoff);
      short8 wl = *(const short8*)(wbl + aoff);
      int svt = s0 + (ks << 5) + ko;
#pragma unroll
      for (int f2 = 0; f2 < 4; ++f2) {
        int d = (f2 << 4) + lh;
        short8 vh = *(const short8*)(VHb + ((size_t)d << 10) + svt);
        short8 vl = *(const short8*)(VLb + ((size_t)d << 10) + svt);
        pv[f2] = mfma16(wh, vh, pv[f2]);
        pv[f2] = mfma16(wl, vh, pv[f2]);
        pv[f2] = mfma16(wh, vl, pv[f2]);
      }
    }
  }

  // ---- epilogue: reduce s-halves, write ctx ----
  __syncthreads();
  f4v* red = (f4v*)uni;
  if (sh == 1) {
#pragma unroll
    for (int f2 = 0; f2 < 4; ++f2) red[((rg << 2) + f2) * 64 + lane] = pv[f2];
  }
  __syncthreads();
  if (sh == 0) {
    int b = bh >> 3, h = bh & 7;
#pragma unroll
    for (int f2 = 0; f2 < 4; ++f2) {
      f4v tot = pv[f2] + red[((rg << 2) + f2) * 64 + lane];
      int d = (f2 << 4) + lh;
#pragma unroll
      for (int r = 0; r < 4; ++r) {
        int l = l0 + (rg << 4) + (g << 2) + r;
        ctx[(((size_t)b * Lq + l) * Hq + h) * 64 + d] = tot[r];
      }
    }
  }
}

// ===========================================================================
extern "C" void kernel_launch(void* const* d_in, const int* in_sizes, int n_in,
                              void* d_out, int out_size, void* d_ws, size_t ws_size,
                              hipStream_t stream) {
  const float* q  = (const float*)d_in[0];
  const float* k  = (const float*)d_in[1];
  const float* v  = (const float*)d_in[2];
  const float* wq = (const float*)d_in[3];
  const float* bq = (const float*)d_in[4];
  const float* wk = (const float*)d_in[5];
  const float* bk = (const float*)d_in[6];

  float* out  = (float*)d_out;
  float* ctx  = out;                    // [B,L,H,D]  = 4,194,304 floats
  float* attn = out + 4194304;          // [B,H,L,S]  = 67,108,864 floats

  // C-matrix parts live in the attn tail (consumed by k_states2q BEFORE
  // k_fused3 overwrites the whole attn region; stream order = barrier).
  float* Cp = attn + (67108864 - 131072);   // 64 bh x 2 parts x 1024 f32

  char* wsb = (char*)d_ws;
  ushort_t* QH  = (ushort_t*)(wsb);
  ushort_t* QL  = (ushort_t*)(wsb + (size_t)4  * 1024 * 1024);
  ushort_t* KH  = (ushort_t*)(wsb + (size_t)8  * 1024 * 1024);
  ushort_t* KL  = (ushort_t*)(wsb + (size_t)12 * 1024 * 1024);
  ushort_t* VTH = (ushort_t*)(wsb + (size_t)16 * 1024 * 1024);
  ushort_t* VTL = (ushort_t*)(wsb + (size_t)24 * 1024 * 1024);

  hipLaunchKernelGGL(k_states2, dim3(256), dim3(256), 0, stream, k, wk, bk, KH, KL);
  hipLaunchKernelGGL(k_csum,    dim3(128), dim3(256), 0, stream, KH, KL, Cp);
  hipLaunchKernelGGL(k_vt,      dim3(1024), dim3(256), 0, stream, v, VTH, VTL);
  hipLaunchKernelGGL(k_states2q, dim3(256), dim3(256), 0, stream, q, wq, bq, Cp, QH, QL);
  hipLaunchKernelGGL(k_fused3,  dim3(2048), dim3(256), 0, stream,
                     QH, QL, KH, KL, VTH, VTL, attn, ctx);
}